// Round 5
// baseline (136.332 us; speedup 1.0000x reference)
//
#include <hip/hip_runtime.h>
#include <hip/hip_bf16.h>

typedef short s16x8 __attribute__((ext_vector_type(8)));
typedef float f32x4 __attribute__((ext_vector_type(4)));
typedef int   i32x4 __attribute__((ext_vector_type(4)));
typedef unsigned short u16;

#define BB 8
#define CC 128
#define HH 48
#define WW 48
#define NN 2304
#define SCALE_L2E 0.12751744f          // log2(e)/sqrt(128)
#define SZ_MAP (BB*CC*NN)              // 2359296 elements
#define NSPLIT 3
#define TILES_PER (18/NSPLIT)

__device__ inline u16 f2bf(float f) {
    unsigned u = __builtin_bit_cast(unsigned, f);
    u = (u + 0x7FFFu + ((u >> 16) & 1u)) >> 16;
    return (u16)u;
}
__device__ inline float bf2f(u16 h) {
    unsigned u = ((unsigned)h) << 16;
    return __builtin_bit_cast(float, u);
}

#define MFMA(a, b, c) __builtin_amdgcn_mfma_f32_16x16x32_bf16(a, b, c, 0, 0, 0)
// DPP rotate-add within each 16-lane row (VALU pipe, no LDS traffic)
#define DPP_ROR_ADD(x, N) { \
    int yi_ = __builtin_amdgcn_update_dpp(0, __builtin_bit_cast(int, x), 0x120 | (N), 0xf, 0xf, true); \
    x += __builtin_bit_cast(float, yi_); }

// ---------------- K1: GroupNorm -> xnT16[b][n][c]  +  weight cast (fused) ----------------
// b = blockIdx.x & 7 so all blocks of batch b land on XCD b (blockid % 8 == b).
__global__ __launch_bounds__(256) void gnprep_kernel(
        const float* __restrict__ x, const float* __restrict__ gw,
        const float* __restrict__ gb, u16* __restrict__ xnT,
        const float* __restrict__ wq, const float* __restrict__ wk,
        const float* __restrict__ wv_, const float* __restrict__ wo,
        u16* __restrict__ w16) {
    int tid = threadIdx.x;
    if (blockIdx.x >= 256) {
        int i = (blockIdx.x - 256) * 256 + tid;   // 0..65535
        int m = i >> 14, r = i & 16383;
        const float* src = (m == 0) ? wq : (m == 1) ? wk : (m == 2) ? wv_ : wo;
        w16[i] = f2bf(src[r]);
        return;
    }
    int b = blockIdx.x & 7, g = blockIdx.x >> 3;
    const float* xb = x + ((size_t)b * CC + g * 4) * NN;
    float v[4][9];
    float s = 0.f, ss = 0.f;
#pragma unroll
    for (int c = 0; c < 4; ++c)
#pragma unroll
        for (int k = 0; k < 9; ++k) {
            float t = xb[c * NN + tid + k * 256];
            v[c][k] = t; s += t; ss += t * t;
        }
#pragma unroll
    for (int o = 32; o > 0; o >>= 1) { s += __shfl_down(s, o); ss += __shfl_down(ss, o); }
    __shared__ float red[8];
    __shared__ float stats[2];
    int wid = tid >> 6;
    if ((tid & 63) == 0) { red[wid * 2] = s; red[wid * 2 + 1] = ss; }
    __syncthreads();
    if (tid == 0) {
        float S = 0.f, SS = 0.f;
        for (int i = 0; i < 4; ++i) { S += red[i * 2]; SS += red[i * 2 + 1]; }
        float mu = S * (1.f / 9216.f);
        float var = SS * (1.f / 9216.f) - mu * mu;
        stats[0] = mu;
        stats[1] = rsqrtf(var + 1e-5f);
    }
    __syncthreads();
    float mu = stats[0], rs = stats[1];
    float sc[4], bi[4];
#pragma unroll
    for (int c = 0; c < 4; ++c) {
        sc[c] = gw[g * 4 + c] * rs;
        bi[c] = gb[g * 4 + c] - mu * sc[c];
    }
#pragma unroll
    for (int k = 0; k < 9; ++k) {
        int n = tid + k * 256;
        ushort4 o;
        o.x = f2bf(v[0][k] * sc[0] + bi[0]);
        o.y = f2bf(v[1][k] * sc[1] + bi[1]);
        o.z = f2bf(v[2][k] * sc[2] + bi[2]);
        o.w = f2bf(v[3][k] * sc[3] + bi[3]);
        *(ushort4*)(xnT + ((size_t)b * NN + n) * CC + g * 4) = o;
    }
}

// ---------------- K2: QKV via MFMA (z=0: q+k, z=1: v) ----------------
// grid (8, 18, 2): b = blockIdx.x (fastest) -> XCD b; n-chunk = blockIdx.y.
// q: natural qT[b][n][c], pre-scaled by log2(e)/sqrt(C).
// k: TILED kt2[b][chunk n/32][ks c/32][slot][c&31], rows permuted so QK-output
//    registers are directly the PV B-fragment: slot(n)=((n&4)<<2)+((n&24)>>1)+(n&3).
// v: TILED vt2[b][chunk n/32][c/16][c&15][n&31].
__global__ __launch_bounds__(256) void qkv_kernel(
        const u16* __restrict__ xnT, const u16* __restrict__ w16,
        const float* __restrict__ bq, const float* __restrict__ bk,
        const float* __restrict__ bv,
        u16* __restrict__ qT, u16* __restrict__ kt2, u16* __restrict__ vt2) {
    int b = blockIdx.x, n0 = blockIdx.y * 128, z = blockIdx.z;
    int tid = threadIdx.x, lane = tid & 63, wvw = tid >> 6;
    int l15 = lane & 15, l4 = lane >> 4;
    const u16* xb = xnT + (size_t)b * NN * CC;

    if (z == 0) {
        const u16* w16q = w16;
        const u16* w16k = w16 + 16384;
        u16* kb = kt2 + (size_t)b * NN * CC;
        s16x8 xa[2][4];
#pragma unroll
        for (int mf = 0; mf < 2; ++mf)
#pragma unroll
            for (int ks = 0; ks < 4; ++ks)
                xa[mf][ks] = *(const s16x8*)(xb + (size_t)(n0 + wvw * 32 + mf * 16 + l15) * CC + ks * 32 + l4 * 8);
#pragma unroll 2
        for (int nf = 0; nf < 8; ++nf) {
            f32x4 aq[2] = {}, ak[2] = {};
#pragma unroll
            for (int ks = 0; ks < 4; ++ks) {
                s16x8 fq = *(const s16x8*)(w16q + (nf * 16 + l15) * CC + ks * 32 + l4 * 8);
                s16x8 fk = *(const s16x8*)(w16k + (nf * 16 + l15) * CC + ks * 32 + l4 * 8);
#pragma unroll
                for (int mf = 0; mf < 2; ++mf) {
                    aq[mf] = MFMA(xa[mf][ks], fq, aq[mf]);
                    ak[mf] = MFMA(xa[mf][ks], fk, ak[mf]);
                }
            }
            int co = nf * 16 + l15;
            float bql = bq[co], bkl = bk[co];
            int chunk = blockIdx.y * 4 + wvw;
#pragma unroll
            for (int mf = 0; mf < 2; ++mf)
#pragma unroll
                for (int r = 0; r < 4; ++r) {
                    int n = n0 + wvw * 32 + mf * 16 + l4 * 4 + r;
                    qT[((size_t)b * NN + n) * CC + co] = f2bf((aq[mf][r] + bql) * SCALE_L2E);
                    // k: tiled + slot-permuted
                    int slot = (l4 & 1) * 16 + mf * 8 + (l4 >> 1) * 4 + r;
                    kb[(size_t)chunk * 4096 + (co >> 5) * 1024 + slot * 32 + (co & 31)]
                        = f2bf(ak[mf][r] + bkl);
                }
        }
    } else {
        const u16* w16v = w16 + 2 * 16384;
        u16* vb = vt2 + (size_t)b * NN * CC;
        s16x8 wa[2][4];
#pragma unroll
        for (int mf = 0; mf < 2; ++mf)
#pragma unroll
            for (int ks = 0; ks < 4; ++ks)
                wa[mf][ks] = *(const s16x8*)(w16v + (wvw * 32 + mf * 16 + l15) * CC + ks * 32 + l4 * 8);
#pragma unroll 2
        for (int nf = 0; nf < 8; ++nf) {
            f32x4 av[2] = {};
#pragma unroll
            for (int ks = 0; ks < 4; ++ks) {
                s16x8 xf = *(const s16x8*)(xb + (size_t)(n0 + nf * 16 + l15) * CC + ks * 32 + l4 * 8);
#pragma unroll
                for (int mf = 0; mf < 2; ++mf) av[mf] = MFMA(wa[mf][ks], xf, av[mf]);
            }
            int chunk = blockIdx.y * 4 + (nf >> 1);
            int n_off = (nf & 1) * 16 + l15;
#pragma unroll
            for (int mf = 0; mf < 2; ++mf) {
                int co = wvw * 32 + mf * 16 + l4 * 4;
#pragma unroll
                for (int r = 0; r < 4; ++r) {
                    int c = co + r;
                    float bvl = bv[c];
                    vb[(size_t)chunk * 4096 + (c >> 4) * 512 + (c & 15) * 32 + n_off]
                        = f2bf(av[mf][r] + bvl);
                }
            }
        }
    }
}

// ---------------- K3: attention — 2-stage tile pipeline (MFMA || VALU overlap) ----------
// grid (8, 48, 3): b fastest -> XCD b. 4 waves/block, wave wvw handles chunks t*4+wvw.
// Per iteration t: softmax(t) VALU/trans work is interleaved (by the scheduler) with
// S(t+1) MFMAs — the two pipes run concurrently inside one wave, collapsing the serial
// S -> softmax -> PV chain that R4 showed costs ~3k cyc/tile solo.
// S = mfma(K,Q): sf[mf][hf] reg r = S[slot mf*16+4l4+r][h=hf*16+l15]; slot permutation
// makes {sf[0][hf], sf[1][hf]} the PV B-frag directly. PV = mfma(V,P).
// FULL(T, SFP, SFQ, KFN, KFP): softmax+PV of tile T from SFP; S(T+1)->SFQ via KFN;
// prefetch K(T+2)->KFP. All names static, nothing address-taken.
#define FULL(T, SFP, SFQ, KFN, KFP) { \
    float p[2][3][4]; \
    _Pragma("unroll") \
    for (int mf = 0; mf < 2; ++mf) \
        _Pragma("unroll") \
        for (int hf = 0; hf < 3; ++hf) \
            _Pragma("unroll") \
            for (int r = 0; r < 4; ++r) p[mf][hf][r] = __builtin_amdgcn_exp2f(SFP[mf][hf][r]); \
    _Pragma("unroll") \
    for (int mf = 0; mf < 2; ++mf) \
        _Pragma("unroll") \
        for (int hf = 0; hf < 3; ++hf) \
            SFQ[mf][hf] = (f32x4){0.f, 0.f, 0.f, 0.f}; \
    __builtin_amdgcn_s_setprio(1); \
    _Pragma("unroll") \
    for (int ks = 0; ks < 4; ++ks) \
        _Pragma("unroll") \
        for (int mf = 0; mf < 2; ++mf) \
            _Pragma("unroll") \
            for (int hf = 0; hf < 3; ++hf) \
                SFQ[mf][hf] = MFMA(KFN[mf][ks], qf[hf][ks], SFQ[mf][hf]); \
    __builtin_amdgcn_s_setprio(0); \
    float den[2][4]; \
    _Pragma("unroll") \
    for (int mf = 0; mf < 2; ++mf) \
        _Pragma("unroll") \
        for (int r = 0; r < 4; ++r) \
            den[mf][r] = p[mf][0][r] + p[mf][1][r] + p[mf][2][r]; \
    const u16* cv = vb + (size_t)((T) * 4 + wvw) * 4096; \
    s16x8 vf[8]; \
    _Pragma("unroll") \
    for (int cf = 0; cf < 8; ++cf) \
        vf[cf] = *(const s16x8*)(cv + cf * 512 + l15 * 32 + l4 * 8); \
    _Pragma("unroll") \
    for (int mf = 0; mf < 2; ++mf) \
        _Pragma("unroll") \
        for (int r = 0; r < 4; ++r) { \
            DPP_ROR_ADD(den[mf][r], 1); \
            DPP_ROR_ADD(den[mf][r], 2); \
            DPP_ROR_ADD(den[mf][r], 4); \
            DPP_ROR_ADD(den[mf][r], 8); \
        } \
    { \
        int tn_ = ((T) + 2 < 18) ? (T) + 2 : 0; \
        const u16* cbn_ = kb + (size_t)(tn_ * 4 + wvw) * 4096; \
        _Pragma("unroll") \
        for (int mf = 0; mf < 2; ++mf) \
            _Pragma("unroll") \
            for (int ks = 0; ks < 4; ++ks) \
                KFP[mf][ks] = *(const s16x8*)(cbn_ + ks * 1024 + (mf * 16 + l15) * 32 + l4 * 8); \
    } \
    float rd[2][4]; \
    _Pragma("unroll") \
    for (int mf = 0; mf < 2; ++mf) \
        _Pragma("unroll") \
        for (int r = 0; r < 4; ++r) rd[mf][r] = __builtin_amdgcn_rcpf(den[mf][r]); \
    s16x8 pbf[3]; \
    _Pragma("unroll") \
    for (int hf = 0; hf < 3; ++hf) { \
        unsigned u0, u1, u2, u3; \
        float a0 = p[0][hf][0] * rd[0][0], a1 = p[0][hf][1] * rd[0][1]; \
        float a2 = p[0][hf][2] * rd[0][2], a3 = p[0][hf][3] * rd[0][3]; \
        float a4 = p[1][hf][0] * rd[1][0], a5 = p[1][hf][1] * rd[1][1]; \
        float a6 = p[1][hf][2] * rd[1][2], a7 = p[1][hf][3] * rd[1][3]; \
        asm("v_cvt_pk_bf16_f32 %0, %1, %2" : "=v"(u0) : "v"(a0), "v"(a1)); \
        asm("v_cvt_pk_bf16_f32 %0, %1, %2" : "=v"(u1) : "v"(a2), "v"(a3)); \
        asm("v_cvt_pk_bf16_f32 %0, %1, %2" : "=v"(u2) : "v"(a4), "v"(a5)); \
        asm("v_cvt_pk_bf16_f32 %0, %1, %2" : "=v"(u3) : "v"(a6), "v"(a7)); \
        i32x4 bb2 = { (int)u0, (int)u1, (int)u2, (int)u3 }; \
        pbf[hf] = __builtin_bit_cast(s16x8, bb2); \
    } \
    __builtin_amdgcn_s_setprio(1); \
    _Pragma("unroll") \
    for (int cf = 0; cf < 8; ++cf) \
        _Pragma("unroll") \
        for (int hf = 0; hf < 3; ++hf) \
            cacc[cf][hf] = MFMA(vf[cf], pbf[hf], cacc[cf][hf]); \
    __builtin_amdgcn_s_setprio(0); \
}

// drain: softmax + PV only (no S-next, no prefetch)
#define DRAIN(T, SFP) { \
    float p[2][3][4]; \
    _Pragma("unroll") \
    for (int mf = 0; mf < 2; ++mf) \
        _Pragma("unroll") \
        for (int hf = 0; hf < 3; ++hf) \
            _Pragma("unroll") \
            for (int r = 0; r < 4; ++r) p[mf][hf][r] = __builtin_amdgcn_exp2f(SFP[mf][hf][r]); \
    float den[2][4]; \
    _Pragma("unroll") \
    for (int mf = 0; mf < 2; ++mf) \
        _Pragma("unroll") \
        for (int r = 0; r < 4; ++r) \
            den[mf][r] = p[mf][0][r] + p[mf][1][r] + p[mf][2][r]; \
    const u16* cv = vb + (size_t)((T) * 4 + wvw) * 4096; \
    s16x8 vf[8]; \
    _Pragma("unroll") \
    for (int cf = 0; cf < 8; ++cf) \
        vf[cf] = *(const s16x8*)(cv + cf * 512 + l15 * 32 + l4 * 8); \
    _Pragma("unroll") \
    for (int mf = 0; mf < 2; ++mf) \
        _Pragma("unroll") \
        for (int r = 0; r < 4; ++r) { \
            DPP_ROR_ADD(den[mf][r], 1); \
            DPP_ROR_ADD(den[mf][r], 2); \
            DPP_ROR_ADD(den[mf][r], 4); \
            DPP_ROR_ADD(den[mf][r], 8); \
        } \
    float rd[2][4]; \
    _Pragma("unroll") \
    for (int mf = 0; mf < 2; ++mf) \
        _Pragma("unroll") \
        for (int r = 0; r < 4; ++r) rd[mf][r] = __builtin_amdgcn_rcpf(den[mf][r]); \
    s16x8 pbf[3]; \
    _Pragma("unroll") \
    for (int hf = 0; hf < 3; ++hf) { \
        unsigned u0, u1, u2, u3; \
        float a0 = p[0][hf][0] * rd[0][0], a1 = p[0][hf][1] * rd[0][1]; \
        float a2 = p[0][hf][2] * rd[0][2], a3 = p[0][hf][3] * rd[0][3]; \
        float a4 = p[1][hf][0] * rd[1][0], a5 = p[1][hf][1] * rd[1][1]; \
        float a6 = p[1][hf][2] * rd[1][2], a7 = p[1][hf][3] * rd[1][3]; \
        asm("v_cvt_pk_bf16_f32 %0, %1, %2" : "=v"(u0) : "v"(a0), "v"(a1)); \
        asm("v_cvt_pk_bf16_f32 %0, %1, %2" : "=v"(u1) : "v"(a2), "v"(a3)); \
        asm("v_cvt_pk_bf16_f32 %0, %1, %2" : "=v"(u2) : "v"(a4), "v"(a5)); \
        asm("v_cvt_pk_bf16_f32 %0, %1, %2" : "=v"(u3) : "v"(a6), "v"(a7)); \
        i32x4 bb2 = { (int)u0, (int)u1, (int)u2, (int)u3 }; \
        pbf[hf] = __builtin_bit_cast(s16x8, bb2); \
    } \
    __builtin_amdgcn_s_setprio(1); \
    _Pragma("unroll") \
    for (int cf = 0; cf < 8; ++cf) \
        _Pragma("unroll") \
        for (int hf = 0; hf < 3; ++hf) \
            cacc[cf][hf] = MFMA(vf[cf], pbf[hf], cacc[cf][hf]); \
    __builtin_amdgcn_s_setprio(0); \
}

__global__ __launch_bounds__(256, 2) void attn_kernel(
        const u16* __restrict__ qT, const u16* __restrict__ kt2,
        const u16* __restrict__ vt2, u16* __restrict__ part) {
    int b = blockIdx.x, w = blockIdx.y, sp = blockIdx.z;
    int tid = threadIdx.x, lane = tid & 63, wvw = tid >> 6;
    int l15 = lane & 15, l4 = lane >> 4;
    __shared__ float red[4 * 48 * 36];   // [q][h][c&31 + pad4]

    const u16* qb = qT + (size_t)b * NN * CC;
    const u16* kb = kt2 + (size_t)b * NN * CC;
    const u16* vb = vt2 + (size_t)b * NN * CC;

    // Q B-frags hoisted: cols h = hf*16 + l15 at fixed w
    s16x8 qf[3][4];
#pragma unroll
    for (int hf = 0; hf < 3; ++hf)
#pragma unroll
        for (int ks = 0; ks < 4; ++ks)
            qf[hf][ks] = *(const s16x8*)(qb + (size_t)((hf * 16 + l15) * WW + w) * CC + ks * 32 + l4 * 8);

    f32x4 cacc[8][3] = {};   // reg r: c = cf*16+4*l4+r ; h = hf*16+l15

    const int tbase = sp * TILES_PER;

    // prologue: K(T0) -> kfA, S(T0) -> sfA, K(T1) -> kfB
    s16x8 kfA[2][4], kfB[2][4];
    f32x4 sfA[2][3], sfB[2][3];
    {
        const u16* cb = kb + (size_t)(tbase * 4 + wvw) * 4096;
#pragma unroll
        for (int mf = 0; mf < 2; ++mf)
#pragma unroll
            for (int ks = 0; ks < 4; ++ks)
                kfA[mf][ks] = *(const s16x8*)(cb + ks * 1024 + (mf * 16 + l15) * 32 + l4 * 8);
    }
#pragma unroll
    for (int mf = 0; mf < 2; ++mf)
#pragma unroll
        for (int hf = 0; hf < 3; ++hf)
            sfA[mf][hf] = (f32x4){0.f, 0.f, 0.f, 0.f};
#pragma unroll
    for (int ks = 0; ks < 4; ++ks)
#pragma unroll
        for (int mf = 0; mf < 2; ++mf)
#pragma unroll
            for (int hf = 0; hf < 3; ++hf)
                sfA[mf][hf] = MFMA(kfA[mf][ks], qf[hf][ks], sfA[mf][hf]);
    {
        const u16* cb = kb + (size_t)((tbase + 1) * 4 + wvw) * 4096;
#pragma unroll
        for (int mf = 0; mf < 2; ++mf)
#pragma unroll
            for (int ks = 0; ks < 4; ++ks)
                kfB[mf][ks] = *(const s16x8*)(cb + ks * 1024 + (mf * 16 + l15) * 32 + l4 * 8);
    }

    // pipelined main: FULL(T): softmax(T) || S(T+1), prefetch K(T+2), PV(T)
#pragma unroll 1
    for (int tt = 0; tt < TILES_PER - 2; tt += 2) {
        int t0 = tbase + tt;
        FULL(t0, sfA, sfB, kfB, kfA)
        int t1 = tbase + tt + 1;
        FULL(t1, sfB, sfA, kfA, kfB)
    }
    {
        int t4 = tbase + TILES_PER - 2;
        FULL(t4, sfA, sfB, kfB, kfA)
        int t5 = tbase + TILES_PER - 1;
        DRAIN(t5, sfB)
    }

    // ---- 4-stage round-robin quadrant reduce (27KB buffer) ----
    // stage s: wave v handles c-quadrant q = (v+s)&3 (cf = 2q, 2q+1)
#pragma unroll
    for (int s = 0; s < 4; ++s) {
        if (s) __syncthreads();
#pragma unroll
        for (int q = 0; q < 4; ++q) {
            if (((q - wvw) & 3) == s) {
#pragma unroll
                for (int i = 0; i < 2; ++i) {
                    int cf = 2 * q + i;
#pragma unroll
                    for (int hf = 0; hf < 3; ++hf) {
                        int addr = q * 1728 + (hf * 16 + l15) * 36 + i * 16 + 4 * l4;
                        f32x4* pp = (f32x4*)&red[addr];
                        if (s == 0) *pp = cacc[cf][hf];
                        else { f32x4 tv = *pp; tv += cacc[cf][hf]; *pp = tv; }
                    }
                }
            }
        }
    }
    __syncthreads();
    // final store: wave v owns quadrant v; lane (l4 = h-sub, l15 = c-pair)
    u16* po = part + (size_t)(b * NSPLIT + sp) * NN * CC;
#pragma unroll
    for (int pass = 0; pass < 12; ++pass) {
        int h = pass * 4 + l4;
        int c = wvw * 32 + l15 * 2;
        float2 v2 = *(float2*)&red[wvw * 1728 + h * 36 + l15 * 2];
        unsigned pk;
        asm("v_cvt_pk_bf16_f32 %0, %1, %2" : "=v"(pk) : "v"(v2.x), "v"(v2.y));
        *(unsigned*)(po + (size_t)(h * WW + w) * CC + c) = pk;
    }
}

// ---------------- K4: partial-reduce + out proj + bias + residual ----------------
// grid (8, 18): b = blockIdx.x -> XCD b, so part[b] (just written by attn on XCD b)
// is read from the same L2.
__global__ __launch_bounds__(256) void out_kernel(
        const u16* __restrict__ part, const u16* __restrict__ w16o,
        const float* __restrict__ bo, const float* __restrict__ x,
        float* __restrict__ out) {
    int b = blockIdx.x, n0 = blockIdx.y * 128;
    int tid = threadIdx.x, lane = tid & 63, wvw = tid >> 6;
    int l15 = lane & 15, l4 = lane >> 4;
    const u16* pb = part + (size_t)b * NSPLIT * NN * CC;
    s16x8 bfr[2][4];
#pragma unroll
    for (int nf = 0; nf < 2; ++nf)
#pragma unroll
        for (int ks = 0; ks < 4; ++ks) {
            size_t off = (size_t)(n0 + wvw * 32 + nf * 16 + l15) * CC + ks * 32 + l4 * 8;
            s16x8 v0 = *(const s16x8*)(pb + off);
            s16x8 v1 = *(const s16x8*)(pb + (size_t)NN * CC + off);
            s16x8 v2 = *(const s16x8*)(pb + (size_t)2 * NN * CC + off);
            s16x8 o;
#pragma unroll
            for (int j = 0; j < 8; ++j)
                o[j] = (short)f2bf(bf2f((u16)v0[j]) + bf2f((u16)v1[j]) + bf2f((u16)v2[j]));
            bfr[nf][ks] = o;
        }
#pragma unroll 2
    for (int mf = 0; mf < 8; ++mf) {
        s16x8 af[4];
#pragma unroll
        for (int ks = 0; ks < 4; ++ks)
            af[ks] = *(const s16x8*)(w16o + (mf * 16 + l15) * CC + ks * 32 + l4 * 8);
        f32x4 acc[2] = {};
#pragma unroll
        for (int ks = 0; ks < 4; ++ks)
#pragma unroll
            for (int nf = 0; nf < 2; ++nf)
                acc[nf] = MFMA(af[ks], bfr[nf][ks], acc[nf]);
#pragma unroll
        for (int nf = 0; nf < 2; ++nf)
#pragma unroll
            for (int r = 0; r < 4; ++r) {
                int co = mf * 16 + l4 * 4 + r;
                int n = n0 + wvw * 32 + nf * 16 + l15;
                size_t idx = ((size_t)b * CC + co) * NN + n;
                out[idx] = acc[nf][r] + bo[co] + x[idx];
            }
    }
}

extern "C" void kernel_launch(void* const* d_in, const int* in_sizes, int n_in,
                              void* d_out, int out_size, void* d_ws, size_t ws_size,
                              hipStream_t stream) {
    const float* x  = (const float*)d_in[0];
    const float* gw = (const float*)d_in[1];
    const float* gb = (const float*)d_in[2];
    const float* wq = (const float*)d_in[3];
    const float* bq = (const float*)d_in[4];
    const float* wk = (const float*)d_in[5];
    const float* bk = (const float*)d_in[6];
    const float* wv_ = (const float*)d_in[7];
    const float* bv = (const float*)d_in[8];
    const float* wo = (const float*)d_in[9];
    const float* bo = (const float*)d_in[10];

    u16* ws   = (u16*)d_ws;
    u16* xnT  = ws;
    u16* qT   = ws + (size_t)SZ_MAP;
    u16* kt2  = ws + (size_t)2 * SZ_MAP;
    u16* vt2  = ws + (size_t)3 * SZ_MAP;
    u16* part = ws + (size_t)4 * SZ_MAP;             // NSPLIT * SZ_MAP bf16
    u16* w16  = ws + (size_t)(4 + NSPLIT) * SZ_MAP;  // 4*16384 bf16
    float* out = (float*)d_out;

    gnprep_kernel<<<512, 256, 0, stream>>>(x, gw, gb, xnT, wq, wk, wv_, wo, w16);
    qkv_kernel<<<dim3(8, 18, 2), 256, 0, stream>>>(xnT, w16, bq, bk, bv, qT, kt2, vt2);
    attn_kernel<<<dim3(8, WW, NSPLIT), 256, 0, stream>>>(qT, kt2, vt2, part);
    out_kernel<<<dim3(8, 18), 256, 0, stream>>>(part, w16 + 3 * 16384, bo, x, out);
}

// Round 6
// 84.783 us; speedup vs baseline: 1.6080x; 1.6080x over previous
//
#include <hip/hip_runtime.h>
#include <hip/hip_bf16.h>

typedef short s16x8 __attribute__((ext_vector_type(8)));
typedef float f32x4 __attribute__((ext_vector_type(4)));
typedef int   i32x4 __attribute__((ext_vector_type(4)));
typedef unsigned short u16;

#define BB 8
#define CC 128
#define HH 48
#define WW 48
#define NN 2304
#define SCALE_L2E 0.12751744f          // log2(e)/sqrt(128)
#define SZ_MAP (BB*CC*NN)              // 2359296 elements
#define NSPLIT 3
#define TILES_PER (18/NSPLIT)

__device__ inline u16 f2bf(float f) {
    unsigned u = __builtin_bit_cast(unsigned, f);
    u = (u + 0x7FFFu + ((u >> 16) & 1u)) >> 16;
    return (u16)u;
}
__device__ inline float bf2f(u16 h) {
    unsigned u = ((unsigned)h) << 16;
    return __builtin_bit_cast(float, u);
}

#define MFMA(a, b, c) __builtin_amdgcn_mfma_f32_16x16x32_bf16(a, b, c, 0, 0, 0)
// DPP rotate-add within each 16-lane row (VALU pipe, no LDS traffic)
#define DPP_ROR_ADD(x, N) { \
    int yi_ = __builtin_amdgcn_update_dpp(0, __builtin_bit_cast(int, x), 0x120 | (N), 0xf, 0xf, true); \
    x += __builtin_bit_cast(float, yi_); }

// ---------------- K1: GroupNorm -> xnT16[b][n][c]  +  weight cast (fused) ----------------
// b = blockIdx.x & 7 so all blocks of batch b land on XCD b (blockid % 8 == b).
__global__ __launch_bounds__(256) void gnprep_kernel(
        const float* __restrict__ x, const float* __restrict__ gw,
        const float* __restrict__ gb, u16* __restrict__ xnT,
        const float* __restrict__ wq, const float* __restrict__ wk,
        const float* __restrict__ wv_, const float* __restrict__ wo,
        u16* __restrict__ w16) {
    int tid = threadIdx.x;
    if (blockIdx.x >= 256) {
        int i = (blockIdx.x - 256) * 256 + tid;   // 0..65535
        int m = i >> 14, r = i & 16383;
        const float* src = (m == 0) ? wq : (m == 1) ? wk : (m == 2) ? wv_ : wo;
        w16[i] = f2bf(src[r]);
        return;
    }
    int b = blockIdx.x & 7, g = blockIdx.x >> 3;
    const float* xb = x + ((size_t)b * CC + g * 4) * NN;
    float v[4][9];
    float s = 0.f, ss = 0.f;
#pragma unroll
    for (int c = 0; c < 4; ++c)
#pragma unroll
        for (int k = 0; k < 9; ++k) {
            float t = xb[c * NN + tid + k * 256];
            v[c][k] = t; s += t; ss += t * t;
        }
#pragma unroll
    for (int o = 32; o > 0; o >>= 1) { s += __shfl_down(s, o); ss += __shfl_down(ss, o); }
    __shared__ float red[8];
    __shared__ float stats[2];
    int wid = tid >> 6;
    if ((tid & 63) == 0) { red[wid * 2] = s; red[wid * 2 + 1] = ss; }
    __syncthreads();
    if (tid == 0) {
        float S = 0.f, SS = 0.f;
        for (int i = 0; i < 4; ++i) { S += red[i * 2]; SS += red[i * 2 + 1]; }
        float mu = S * (1.f / 9216.f);
        float var = SS * (1.f / 9216.f) - mu * mu;
        stats[0] = mu;
        stats[1] = rsqrtf(var + 1e-5f);
    }
    __syncthreads();
    float mu = stats[0], rs = stats[1];
    float sc[4], bi[4];
#pragma unroll
    for (int c = 0; c < 4; ++c) {
        sc[c] = gw[g * 4 + c] * rs;
        bi[c] = gb[g * 4 + c] - mu * sc[c];
    }
#pragma unroll
    for (int k = 0; k < 9; ++k) {
        int n = tid + k * 256;
        ushort4 o;
        o.x = f2bf(v[0][k] * sc[0] + bi[0]);
        o.y = f2bf(v[1][k] * sc[1] + bi[1]);
        o.z = f2bf(v[2][k] * sc[2] + bi[2]);
        o.w = f2bf(v[3][k] * sc[3] + bi[3]);
        *(ushort4*)(xnT + ((size_t)b * NN + n) * CC + g * 4) = o;
    }
}

// ---------------- K2: QKV via MFMA (z=0: q+k, z=1: v) — coalesced ushort4 stores ------
// grid (8, 18, 2): b = blockIdx.x (fastest) -> XCD b; n-chunk = blockIdx.y.
// Operand-swapped MFMAs: D rows = first-arg rows, D cols = second-arg rows
// (A/B fragments share the same per-lane register layout, so loads are unchanged).
// After swap each lane holds 4 CONSECUTIVE fast-axis elements of every output layout
// -> all epilogue stores are single ushort4 (8B) writes.
// q: natural qT[b][n][c], pre-scaled by log2(e)/sqrt(C).
// k: TILED kt2[b][chunk n/32][ks c/32][slot][c&31], slot(n)=((n&4)<<2)+((n&24)>>1)+(n&3).
// v: TILED vt2[b][chunk n/32][c/16][c&15][n&31].
__global__ __launch_bounds__(256) void qkv_kernel(
        const u16* __restrict__ xnT, const u16* __restrict__ w16,
        const float* __restrict__ bq, const float* __restrict__ bk,
        const float* __restrict__ bv,
        u16* __restrict__ qT, u16* __restrict__ kt2, u16* __restrict__ vt2) {
    int b = blockIdx.x, n0 = blockIdx.y * 128, z = blockIdx.z;
    int tid = threadIdx.x, lane = tid & 63, wvw = tid >> 6;
    int l15 = lane & 15, l4 = lane >> 4;
    const u16* xb = xnT + (size_t)b * NN * CC;

    if (z == 0) {
        const u16* w16q = w16;
        const u16* w16k = w16 + 16384;
        u16* kb = kt2 + (size_t)b * NN * CC;
        s16x8 xa[2][4];
#pragma unroll
        for (int mf = 0; mf < 2; ++mf)
#pragma unroll
            for (int ks = 0; ks < 4; ++ks)
                xa[mf][ks] = *(const s16x8*)(xb + (size_t)(n0 + wvw * 32 + mf * 16 + l15) * CC + ks * 32 + l4 * 8);
        int chunk = blockIdx.y * 4 + wvw;
#pragma unroll 2
        for (int nf = 0; nf < 8; ++nf) {
            f32x4 aq[2] = {}, ak[2] = {};
#pragma unroll
            for (int ks = 0; ks < 4; ++ks) {
                s16x8 fq = *(const s16x8*)(w16q + (nf * 16 + l15) * CC + ks * 32 + l4 * 8);
                s16x8 fk = *(const s16x8*)(w16k + (nf * 16 + l15) * CC + ks * 32 + l4 * 8);
#pragma unroll
                for (int mf = 0; mf < 2; ++mf) {
                    aq[mf] = MFMA(fq, xa[mf][ks], aq[mf]);   // rows=co, cols=n
                    ak[mf] = MFMA(fk, xa[mf][ks], ak[mf]);
                }
            }
            // lane: co = nf*16 + l4*4 + r (consecutive r) ; n = n0 + wvw*32 + mf*16 + l15
            int cob = nf * 16 + l4 * 4;
            float4 bq4 = *(const float4*)(bq + cob);
            float4 bk4 = *(const float4*)(bk + cob);
#pragma unroll
            for (int mf = 0; mf < 2; ++mf) {
                int n = n0 + wvw * 32 + mf * 16 + l15;
                ushort4 qo;
                qo.x = f2bf((aq[mf][0] + bq4.x) * SCALE_L2E);
                qo.y = f2bf((aq[mf][1] + bq4.y) * SCALE_L2E);
                qo.z = f2bf((aq[mf][2] + bq4.z) * SCALE_L2E);
                qo.w = f2bf((aq[mf][3] + bq4.w) * SCALE_L2E);
                *(ushort4*)(qT + ((size_t)b * NN + n) * CC + cob) = qo;
                int n5 = mf * 16 + l15;
                int slot = ((n5 & 4) << 2) + ((n5 & 24) >> 1) + (n5 & 3);
                ushort4 ko;
                ko.x = f2bf(ak[mf][0] + bk4.x);
                ko.y = f2bf(ak[mf][1] + bk4.y);
                ko.z = f2bf(ak[mf][2] + bk4.z);
                ko.w = f2bf(ak[mf][3] + bk4.w);
                *(ushort4*)(kb + (size_t)chunk * 4096 + (cob >> 5) * 1024 + slot * 32 + (cob & 31)) = ko;
            }
        }
    } else {
        const u16* w16v = w16 + 2 * 16384;
        u16* vb = vt2 + (size_t)b * NN * CC;
        s16x8 wa[2][4];
#pragma unroll
        for (int mf = 0; mf < 2; ++mf)
#pragma unroll
            for (int ks = 0; ks < 4; ++ks)
                wa[mf][ks] = *(const s16x8*)(w16v + (wvw * 32 + mf * 16 + l15) * CC + ks * 32 + l4 * 8);
        // c is fixed per (lane, mf) after the swap -> bias scalar per mf
        float bvl[2];
        bvl[0] = bv[wvw * 32 + l15];
        bvl[1] = bv[wvw * 32 + 16 + l15];
#pragma unroll 2
        for (int nf = 0; nf < 8; ++nf) {
            f32x4 av[2] = {};
#pragma unroll
            for (int ks = 0; ks < 4; ++ks) {
                s16x8 xf = *(const s16x8*)(xb + (size_t)(n0 + nf * 16 + l15) * CC + ks * 32 + l4 * 8);
#pragma unroll
                for (int mf = 0; mf < 2; ++mf) av[mf] = MFMA(xf, wa[mf][ks], av[mf]);  // rows=n, cols=c
            }
            // lane: n = n0 + nf*16 + l4*4 + r (consecutive r) ; c = wvw*32 + mf*16 + l15
            int chunk = blockIdx.y * 4 + (nf >> 1);
            int nlo = (nf & 1) * 16 + l4 * 4;
#pragma unroll
            for (int mf = 0; mf < 2; ++mf) {
                ushort4 vo;
                vo.x = f2bf(av[mf][0] + bvl[mf]);
                vo.y = f2bf(av[mf][1] + bvl[mf]);
                vo.z = f2bf(av[mf][2] + bvl[mf]);
                vo.w = f2bf(av[mf][3] + bvl[mf]);
                *(ushort4*)(vb + (size_t)chunk * 4096 + (wvw * 2 + mf) * 512 + l15 * 32 + nlo) = vo;
            }
        }
    }
}

// ---------------- K3: attention — K reg double-buffer + b->XCD locality (R3 proven) ----
// grid (8, 48, 3): b = blockIdx.x (fastest) -> all 144 blocks of batch b on XCD b.
// S = mfma(K,Q): sf[mf][hf] reg r at lane(l4,l15) = S[slot mf*16+4l4+r][h=hf*16+l15];
// slot permutation makes {sf[0][hf], sf[1][hf]} the PV B-frag directly (k = n = 8*l4+j).
// PV = mfma(V,P): cacc[cf][hf] reg r = ctx[c = cf*16+4*l4+r][h = hf*16+l15].
// Pipeline: V(t) issued at top; K(t+1) issued right after S(t). Ping-pong kfA/kfB via
// macro text expansion — all array indices compile-time constant, nothing address-taken.
#define TILE_BODY(T, KFC, KFN) { \
    const u16* cv = vb + (size_t)((T) * 4 + wvw) * 4096; \
    s16x8 vf[8]; \
    _Pragma("unroll") \
    for (int cf = 0; cf < 8; ++cf) \
        vf[cf] = *(const s16x8*)(cv + cf * 512 + l15 * 32 + l4 * 8); \
    f32x4 sf[2][3] = {}; \
    __builtin_amdgcn_s_setprio(1); \
    _Pragma("unroll") \
    for (int ks = 0; ks < 4; ++ks) \
        _Pragma("unroll") \
        for (int mf = 0; mf < 2; ++mf) \
            _Pragma("unroll") \
            for (int hf = 0; hf < 3; ++hf) \
                sf[mf][hf] = MFMA(KFC[mf][ks], qf[hf][ks], sf[mf][hf]); \
    __builtin_amdgcn_s_setprio(0); \
    { \
        int tn_ = ((T) + 1 < 18) ? (T) + 1 : 0; \
        const u16* cbn_ = kb + (size_t)(tn_ * 4 + wvw) * 4096; \
        _Pragma("unroll") \
        for (int mf = 0; mf < 2; ++mf) \
            _Pragma("unroll") \
            for (int ks = 0; ks < 4; ++ks) \
                KFN[mf][ks] = *(const s16x8*)(cbn_ + ks * 1024 + (mf * 16 + l15) * 32 + l4 * 8); \
    } \
    float p[2][3][4]; \
    _Pragma("unroll") \
    for (int mf = 0; mf < 2; ++mf) \
        _Pragma("unroll") \
        for (int hf = 0; hf < 3; ++hf) \
            _Pragma("unroll") \
            for (int r = 0; r < 4; ++r) p[mf][hf][r] = __builtin_amdgcn_exp2f(sf[mf][hf][r]); \
    float den[2][4]; \
    _Pragma("unroll") \
    for (int mf = 0; mf < 2; ++mf) \
        _Pragma("unroll") \
        for (int r = 0; r < 4; ++r) \
            den[mf][r] = p[mf][0][r] + p[mf][1][r] + p[mf][2][r]; \
    _Pragma("unroll") \
    for (int mf = 0; mf < 2; ++mf) \
        _Pragma("unroll") \
        for (int r = 0; r < 4; ++r) { \
            DPP_ROR_ADD(den[mf][r], 1); \
            DPP_ROR_ADD(den[mf][r], 2); \
            DPP_ROR_ADD(den[mf][r], 4); \
            DPP_ROR_ADD(den[mf][r], 8); \
        } \
    float rd[2][4]; \
    _Pragma("unroll") \
    for (int mf = 0; mf < 2; ++mf) \
        _Pragma("unroll") \
        for (int r = 0; r < 4; ++r) rd[mf][r] = __builtin_amdgcn_rcpf(den[mf][r]); \
    s16x8 pbf[3]; \
    _Pragma("unroll") \
    for (int hf = 0; hf < 3; ++hf) { \
        unsigned u0, u1, u2, u3; \
        float a0 = p[0][hf][0] * rd[0][0], a1 = p[0][hf][1] * rd[0][1]; \
        float a2 = p[0][hf][2] * rd[0][2], a3 = p[0][hf][3] * rd[0][3]; \
        float a4 = p[1][hf][0] * rd[1][0], a5 = p[1][hf][1] * rd[1][1]; \
        float a6 = p[1][hf][2] * rd[1][2], a7 = p[1][hf][3] * rd[1][3]; \
        asm("v_cvt_pk_bf16_f32 %0, %1, %2" : "=v"(u0) : "v"(a0), "v"(a1)); \
        asm("v_cvt_pk_bf16_f32 %0, %1, %2" : "=v"(u1) : "v"(a2), "v"(a3)); \
        asm("v_cvt_pk_bf16_f32 %0, %1, %2" : "=v"(u2) : "v"(a4), "v"(a5)); \
        asm("v_cvt_pk_bf16_f32 %0, %1, %2" : "=v"(u3) : "v"(a6), "v"(a7)); \
        i32x4 bb2 = { (int)u0, (int)u1, (int)u2, (int)u3 }; \
        pbf[hf] = __builtin_bit_cast(s16x8, bb2); \
    } \
    __builtin_amdgcn_s_setprio(1); \
    _Pragma("unroll") \
    for (int cf = 0; cf < 8; ++cf) \
        _Pragma("unroll") \
        for (int hf = 0; hf < 3; ++hf) \
            cacc[cf][hf] = MFMA(vf[cf], pbf[hf], cacc[cf][hf]); \
    __builtin_amdgcn_s_setprio(0); \
}

__global__ __launch_bounds__(256, 2) void attn_kernel(
        const u16* __restrict__ qT, const u16* __restrict__ kt2,
        const u16* __restrict__ vt2, u16* __restrict__ part) {
    int b = blockIdx.x, w = blockIdx.y, sp = blockIdx.z;
    int tid = threadIdx.x, lane = tid & 63, wvw = tid >> 6;
    int l15 = lane & 15, l4 = lane >> 4;
    __shared__ float red[4 * 48 * 36];   // [q][h][c&31 + pad4]

    const u16* qb = qT + (size_t)b * NN * CC;
    const u16* kb = kt2 + (size_t)b * NN * CC;
    const u16* vb = vt2 + (size_t)b * NN * CC;

    // Q B-frags hoisted: cols h = hf*16 + l15 at fixed w
    s16x8 qf[3][4];
#pragma unroll
    for (int hf = 0; hf < 3; ++hf)
#pragma unroll
        for (int ks = 0; ks < 4; ++ks)
            qf[hf][ks] = *(const s16x8*)(qb + (size_t)((hf * 16 + l15) * WW + w) * CC + ks * 32 + l4 * 8);

    f32x4 cacc[8][3] = {};   // reg r: c = cf*16+4*l4+r ; h = hf*16+l15

    const int tbase = sp * TILES_PER;

    // prologue: preload K(tbase)
    s16x8 kfA[2][4], kfB[2][4];
    {
        const u16* cb = kb + (size_t)(tbase * 4 + wvw) * 4096;
#pragma unroll
        for (int mf = 0; mf < 2; ++mf)
#pragma unroll
            for (int ks = 0; ks < 4; ++ks)
                kfA[mf][ks] = *(const s16x8*)(cb + ks * 1024 + (mf * 16 + l15) * 32 + l4 * 8);
    }

#pragma unroll 1
    for (int tt = 0; tt < TILES_PER; tt += 2) {
        int t0 = tbase + tt;
        TILE_BODY(t0, kfA, kfB)
        int t1 = tbase + tt + 1;
        TILE_BODY(t1, kfB, kfA)
    }

    // ---- 4-stage round-robin quadrant reduce (27KB buffer) ----
    // stage s: wave v handles c-quadrant q = (v+s)&3 (cf = 2q, 2q+1)
#pragma unroll
    for (int s = 0; s < 4; ++s) {
        if (s) __syncthreads();
#pragma unroll
        for (int q = 0; q < 4; ++q) {
            if (((q - wvw) & 3) == s) {
#pragma unroll
                for (int i = 0; i < 2; ++i) {
                    int cf = 2 * q + i;
#pragma unroll
                    for (int hf = 0; hf < 3; ++hf) {
                        int addr = q * 1728 + (hf * 16 + l15) * 36 + i * 16 + 4 * l4;
                        f32x4* pp = (f32x4*)&red[addr];
                        if (s == 0) *pp = cacc[cf][hf];
                        else { f32x4 tv = *pp; tv += cacc[cf][hf]; *pp = tv; }
                    }
                }
            }
        }
    }
    __syncthreads();
    // final store: wave v owns quadrant v; lane (l4 = h-sub, l15 = c-pair)
    u16* po = part + (size_t)(b * NSPLIT + sp) * NN * CC;
#pragma unroll
    for (int pass = 0; pass < 12; ++pass) {
        int h = pass * 4 + l4;
        int c = wvw * 32 + l15 * 2;
        float2 v2 = *(float2*)&red[wvw * 1728 + h * 36 + l15 * 2];
        unsigned pk;
        asm("v_cvt_pk_bf16_f32 %0, %1, %2" : "=v"(pk) : "v"(v2.x), "v"(v2.y));
        *(unsigned*)(po + (size_t)(h * WW + w) * CC + c) = pk;
    }
}

// ---------------- K4: partial-reduce + out proj + bias + residual ----------------
// grid (8, 18): b = blockIdx.x -> XCD b, so part[b] (just written by attn on XCD b)
// is read from the same L2.
__global__ __launch_bounds__(256) void out_kernel(
        const u16* __restrict__ part, const u16* __restrict__ w16o,
        const float* __restrict__ bo, const float* __restrict__ x,
        float* __restrict__ out) {
    int b = blockIdx.x, n0 = blockIdx.y * 128;
    int tid = threadIdx.x, lane = tid & 63, wvw = tid >> 6;
    int l15 = lane & 15, l4 = lane >> 4;
    const u16* pb = part + (size_t)b * NSPLIT * NN * CC;
    s16x8 bfr[2][4];
#pragma unroll
    for (int nf = 0; nf < 2; ++nf)
#pragma unroll
        for (int ks = 0; ks < 4; ++ks) {
            size_t off = (size_t)(n0 + wvw * 32 + nf * 16 + l15) * CC + ks * 32 + l4 * 8;
            s16x8 v0 = *(const s16x8*)(pb + off);
            s16x8 v1 = *(const s16x8*)(pb + (size_t)NN * CC + off);
            s16x8 v2 = *(const s16x8*)(pb + (size_t)2 * NN * CC + off);
            s16x8 o;
#pragma unroll
            for (int j = 0; j < 8; ++j)
                o[j] = (short)f2bf(bf2f((u16)v0[j]) + bf2f((u16)v1[j]) + bf2f((u16)v2[j]));
            bfr[nf][ks] = o;
        }
#pragma unroll 2
    for (int mf = 0; mf < 8; ++mf) {
        s16x8 af[4];
#pragma unroll
        for (int ks = 0; ks < 4; ++ks)
            af[ks] = *(const s16x8*)(w16o + (mf * 16 + l15) * CC + ks * 32 + l4 * 8);
        f32x4 acc[2] = {};
#pragma unroll
        for (int ks = 0; ks < 4; ++ks)
#pragma unroll
            for (int nf = 0; nf < 2; ++nf)
                acc[nf] = MFMA(af[ks], bfr[nf][ks], acc[nf]);
#pragma unroll
        for (int nf = 0; nf < 2; ++nf)
#pragma unroll
            for (int r = 0; r < 4; ++r) {
                int co = mf * 16 + l4 * 4 + r;
                int n = n0 + wvw * 32 + nf * 16 + l15;
                size_t idx = ((size_t)b * CC + co) * NN + n;
                out[idx] = acc[nf][r] + bo[co] + x[idx];
            }
    }
}

extern "C" void kernel_launch(void* const* d_in, const int* in_sizes, int n_in,
                              void* d_out, int out_size, void* d_ws, size_t ws_size,
                              hipStream_t stream) {
    const float* x  = (const float*)d_in[0];
    const float* gw = (const float*)d_in[1];
    const float* gb = (const float*)d_in[2];
    const float* wq = (const float*)d_in[3];
    const float* bq = (const float*)d_in[4];
    const float* wk = (const float*)d_in[5];
    const float* bk = (const float*)d_in[6];
    const float* wv_ = (const float*)d_in[7];
    const float* bv = (const float*)d_in[8];
    const float* wo = (const float*)d_in[9];
    const float* bo = (const float*)d_in[10];

    u16* ws   = (u16*)d_ws;
    u16* xnT  = ws;
    u16* qT   = ws + (size_t)SZ_MAP;
    u16* kt2  = ws + (size_t)2 * SZ_MAP;
    u16* vt2  = ws + (size_t)3 * SZ_MAP;
    u16* part = ws + (size_t)4 * SZ_MAP;             // NSPLIT * SZ_MAP bf16
    u16* w16  = ws + (size_t)(4 + NSPLIT) * SZ_MAP;  // 4*16384 bf16
    float* out = (float*)d_out;

    gnprep_kernel<<<512, 256, 0, stream>>>(x, gw, gb, xnT, wq, wk, wv_, wo, w16);
    qkv_kernel<<<dim3(8, 18, 2), 256, 0, stream>>>(xnT, w16, bq, bk, bv, qT, kt2, vt2);
    attn_kernel<<<dim3(8, WW, NSPLIT), 256, 0, stream>>>(qT, kt2, vt2, part);
    out_kernel<<<dim3(8, 18), 256, 0, stream>>>(part, w16 + 3 * 16384, bo, x, out);
}